// Round 6
// baseline (812.521 us; speedup 1.0000x reference)
//
#include <hip/hip_runtime.h>
#include <hip/hip_cooperative_groups.h>
#include <math.h>

#define BB 64
#define CC 512
#define HW 784
#define DD 512
#define GR 512
#define KK 20

namespace cg = cooperative_groups;

typedef __bf16 bf16x8 __attribute__((ext_vector_type(8)));
typedef float f32x16 __attribute__((ext_vector_type(16)));

__device__ inline unsigned short bf16rtn(float f) {
  unsigned int u = __builtin_bit_cast(unsigned int, f);
  unsigned int r = (u + 0x7FFFu + ((u >> 16) & 1u)) >> 16;
  return (unsigned short)r;
}

// ---------------------------------------------------------------------------
// Gram: G[b] = xf[b] @ xf[b]^T / 784, plain bf16 MFMA (RTN).
// 128x128 tiles, upper-tri pairs mirror-stored. 1D grid 640 with XCD-aware
// decode: bid%8 = XCD (round-robin dispatch), so all 10 tile-pair blocks of
// one batch land on one XCD -> X panels (1.6 MB/batch) L2-resident across
// the 4x re-reads. 512 thr, 64 KB dyn LDS -> 2 blocks/CU. BK=112.
// ---------------------------------------------------------------------------
__global__ __launch_bounds__(512) void gram_mfma(const float* __restrict__ X,
                                                 float* __restrict__ G) {
  extern __shared__ unsigned short lds[];
  unsigned short* __restrict__ Apl = lds;           // [128][128] (112 used)
  unsigned short* __restrict__ Bpl = lds + 16384;

  const int bid = blockIdx.x;          // 640 = 8 xcd * 8 b * 10 pairs
  const int xcd = bid & 7;
  const int kslot = bid >> 3;          // 0..79
  const int b = xcd * 8 + kslot / 10;
  int lin = kslot % 10;
  int i = 0;
  while (lin >= 4 - i) { lin -= 4 - i; ++i; }
  const int j = i + lin;  // i <= j
  const bool diag = (i == j);

  const float* __restrict__ xb = X + (size_t)b * (CC * HW);
  const int tid = threadIdx.x;
  const int w = tid >> 6, l = tid & 63;
  const int wr = w >> 1;  // 0..3: 32-row block
  const int wc = w & 1;   // 0..1: 64-col block

  f32x16 acc0 = {};
  f32x16 acc1 = {};

  const int sr = tid >> 2;        // 0..127 staging row
  const int lane4 = tid & 3;

  for (int it = 0; it < 7; ++it) {
    const int k0 = it * 112;
    __syncthreads();
#pragma unroll
    for (int q = 0; q < 7; ++q) {
      const int pos = lane4 + q * 4;          // float4 index 0..27
      const int chunk = pos >> 1;
      const int soff =
          sr * 128 + (((chunk ^ (sr & 7)) << 3) | ((pos & 1) << 2));
#pragma unroll
      for (int pnl = 0; pnl < 2; ++pnl) {
        if (pnl && diag) break;
        const int rowbase = (pnl ? j : i) * 128;
        float4 v =
            *(const float4*)(xb + (size_t)(rowbase + sr) * HW + k0 + pos * 4);
        unsigned int p0 = bf16rtn(v.x) | ((unsigned int)bf16rtn(v.y) << 16);
        unsigned int p1 = bf16rtn(v.z) | ((unsigned int)bf16rtn(v.w) << 16);
        *(uint2*)((pnl ? Bpl : Apl) + soff) = make_uint2(p0, p1);
      }
    }
    __syncthreads();
    const unsigned short* __restrict__ bP = diag ? Apl : Bpl;
#pragma unroll
    for (int ks = 0; ks < 7; ++ks) {
      const int chunk = ks * 2 + (l >> 5);
      const int ar = wr * 32 + (l & 31);
      bf16x8 a = *(const bf16x8*)(Apl + ar * 128 + ((chunk ^ (ar & 7)) << 3));
      const int br0 = wc * 64 + (l & 31);
      const int br1 = br0 + 32;
      bf16x8 b0 = *(const bf16x8*)(bP + br0 * 128 + ((chunk ^ (br0 & 7)) << 3));
      bf16x8 b1 = *(const bf16x8*)(bP + br1 * 128 + ((chunk ^ (br1 & 7)) << 3));
      acc0 = __builtin_amdgcn_mfma_f32_32x32x16_bf16(a, b0, acc0, 0, 0, 0);
      acc1 = __builtin_amdgcn_mfma_f32_32x32x16_bf16(a, b1, acc1, 0, 0, 0);
    }
  }

  const float sc = 1.0f / (float)HW;
  float* __restrict__ gb = G + (size_t)b * (CC * CC);
  const int rowbase = i * 128 + wr * 32 + 4 * (l >> 5);
  const int colbase = j * 128 + wc * 64 + (l & 31);
#pragma unroll
  for (int n = 0; n < 2; ++n) {
    const f32x16 a = n ? acc1 : acc0;
#pragma unroll
    for (int reg = 0; reg < 16; ++reg) {
      const int row = rowbase + (reg & 3) + 8 * (reg >> 2);
      const int col = colbase + n * 32;
      const float v = a[reg] * sc;
      gb[(size_t)row * CC + col] = v;
      if (!diag) gb[(size_t)col * CC + row] = v;
    }
  }
}

// ---------------------------------------------------------------------------
// U kernel v2: U[cd][k] = sum_r W[cd][r]*C[k][r].  BK=32 (128 B per row-visit)
// -> each 128 B line of gram_w read exactly once. grid 1024, block 256.
// ---------------------------------------------------------------------------
__global__ __launch_bounds__(256) void u_kernel2(const float* __restrict__ W,
                                                 const float* __restrict__ C,
                                                 float* __restrict__ U) {
  __shared__ float Ws[256][36];
  __shared__ float Ct[20][36];

  const int tid = threadIdx.x;
  const int rt = tid >> 2, kq = tid & 3;
  const size_t row0 = (size_t)blockIdx.x << 8;

  float acc[4][5] = {};

  for (int k0 = 0; k0 < GR; k0 += 32) {
    __syncthreads();
#pragma unroll
    for (int q = 0; q < 8; ++q) {
      const int row = q * 32 + (tid >> 3);
      const int col = (tid & 7) * 4;
      float4 w4 = *(const float4*)(W + (row0 + row) * GR + k0 + col);
      *(float4*)&Ws[row][col] = w4;
    }
    if (tid < 160) {
      const int k = tid >> 3, pp = tid & 7;
      *(float4*)&Ct[k][pp * 4] = *(const float4*)(C + k * GR + k0 + pp * 4);
    }
    __syncthreads();
#pragma unroll
    for (int kk4 = 0; kk4 < 8; ++kk4) {
      float4 wv[4];
#pragma unroll
      for (int u = 0; u < 4; ++u)
        wv[u] = *(const float4*)&Ws[rt + u * 64][kk4 * 4];
#pragma unroll
      for (int q = 0; q < 5; ++q) {
        float4 c4 = *(const float4*)&Ct[kq * 5 + q][kk4 * 4];
#pragma unroll
        for (int u = 0; u < 4; ++u) {
          acc[u][q] = fmaf(wv[u].x, c4.x, acc[u][q]);
          acc[u][q] = fmaf(wv[u].y, c4.y, acc[u][q]);
          acc[u][q] = fmaf(wv[u].z, c4.z, acc[u][q]);
          acc[u][q] = fmaf(wv[u].w, c4.w, acc[u][q]);
        }
      }
    }
  }
#pragma unroll
  for (int u = 0; u < 4; ++u)
#pragma unroll
    for (int q = 0; q < 5; ++q)
      U[(row0 + rt + u * 64) * KK + kq * 5 + q] = acc[u][q];
}

// ---------------------------------------------------------------------------
// scores: partial[slice][k][b] = sum_{cd in slice} G[b][cd]*U[cd][k]
// grid 512 (slices of 512 cd), block 128.  (identical to R2/R5)
// ---------------------------------------------------------------------------
__global__ __launch_bounds__(128) void scores_k(const float* __restrict__ G,
                                                const float* __restrict__ U,
                                                float* __restrict__ P) {
  __shared__ float Gs[64][68];
  __shared__ float Ut[20][68];

  const int tid = threadIdx.x;
  const int bsub = tid & 31, kg = tid >> 5;
  const size_t s0 = (size_t)blockIdx.x << 9;

  float acc[2][5] = {};

  for (int c0 = 0; c0 < 512; c0 += 64) {
    __syncthreads();
#pragma unroll
    for (int q = 0; q < 8; ++q) {
      int bb = q * 8 + (tid >> 4);
      float4 g4 = *(const float4*)(G + (size_t)bb * (CC * CC) + s0 + c0 +
                                   (tid & 15) * 4);
      *(float4*)&Gs[bb][(tid & 15) * 4] = g4;
    }
#pragma unroll
    for (int e = 0; e < 10; ++e) {
      int f = e * 128 + tid;
      float val = U[(s0 + c0) * KK + f];
      Ut[f % 20][f / 20] = val;
    }
    __syncthreads();
#pragma unroll
    for (int kk4 = 0; kk4 < 16; ++kk4) {
      float4 ga = *(const float4*)&Gs[bsub][kk4 * 4];
      float4 gb2 = *(const float4*)&Gs[bsub + 32][kk4 * 4];
#pragma unroll
      for (int q = 0; q < 5; ++q) {
        float4 c4 = *(const float4*)&Ut[kg * 5 + q][kk4 * 4];
        acc[0][q] = fmaf(ga.x, c4.x, acc[0][q]);
        acc[0][q] = fmaf(ga.y, c4.y, acc[0][q]);
        acc[0][q] = fmaf(ga.z, c4.z, acc[0][q]);
        acc[0][q] = fmaf(ga.w, c4.w, acc[0][q]);
        acc[1][q] = fmaf(gb2.x, c4.x, acc[1][q]);
        acc[1][q] = fmaf(gb2.y, c4.y, acc[1][q]);
        acc[1][q] = fmaf(gb2.z, c4.z, acc[1][q]);
        acc[1][q] = fmaf(gb2.w, c4.w, acc[1][q]);
      }
    }
  }
#pragma unroll
  for (int q = 0; q < 5; ++q) {
    P[(size_t)blockIdx.x * 1280 + (kg * 5 + q) * 64 + bsub] = acc[0][q];
    P[(size_t)blockIdx.x * 1280 + (kg * 5 + q) * 64 + bsub + 32] = acc[1][q];
  }
}

// ---------------------------------------------------------------------------
// Cooperative MLP: the entire post-scores chain in one kernel, stages
// separated by grid.sync(). Stage bodies are ports of R5's kernels.
// grid 128 x 256 thr.
// ---------------------------------------------------------------------------
struct MlpParams {
  const float* x_embed;
  const float* attn_w1; const float* attn_b1;
  const float* attn_w2; const float* attn_b2;
  const float* ln_ff_g; const float* ln_ff_b;
  const float* ff_w1; const float* ff_b1;
  const float* ff_w2; const float* ff_b2;
  const float* gram_b; const float* centers;
  const float* gm_w; const float* gm_b;
  const float* ln1_g; const float* ln1_b;
  const float* m1_w; const float* m1_b;
  const float* m2_w1; const float* m2_b1;
  const float* m2_w2; const float* m2_b2;
  const float* out_w; const float* out_b;
  const float* P;
  float* offs; float* h1; float* x_attn; float* xln; float* f1;
  float* x_main; float* x_fused; float* x_h; float* xln1; float* hh;
  float* h2; float* h3; float* out;
};

// lin: out = post(act(A@W + bias)); tile = 64 cols x 16 rows. (R2/R5 body)
__device__ __forceinline__ void lin_stage(
    int bid, const float* __restrict__ A, const float* __restrict__ W,
    const float* __restrict__ bias, const float* __restrict__ gate,
    const float* __restrict__ res, float* __restrict__ out, int N, int K,
    int act, float* __restrict__ As /* [16*34] */) {
  const int nbx = (N + 63) >> 6;
  if (bid >= nbx * 4) return;
  const int bx = bid % nbx, by = bid / nbx;
  const int tid = threadIdx.x;
  const int tx = tid & 63, ty = tid >> 6;
  const int n = bx * 64 + tx;
  const int r0 = by * 16;
  float acc[4] = {0.f, 0.f, 0.f, 0.f};
  const int t2 = tid * 2;
  const int srr = t2 >> 5, skk = t2 & 31;

  for (int k0 = 0; k0 < K; k0 += 32) {
    __syncthreads();
    float2 a2 = *(const float2*)(A + (size_t)(r0 + srr) * K + k0 + skk);
    As[srr * 34 + skk] = a2.x;
    As[srr * 34 + skk + 1] = a2.y;
    __syncthreads();
    if (n < N) {
#pragma unroll
      for (int kk = 0; kk < 32; ++kk) {
        float w = W[(size_t)(k0 + kk) * N + n];
#pragma unroll
        for (int u = 0; u < 4; ++u)
          acc[u] = fmaf(As[(ty * 4 + u) * 34 + kk], w, acc[u]);
      }
    }
  }
  if (n < N) {
    float bv = bias[n];
#pragma unroll
    for (int u = 0; u < 4; ++u) {
      int r = r0 + ty * 4 + u;
      float v = acc[u] + bv;
      if (act == 1) v = v > 0.f ? v : 0.f;
      else if (act == 2) v = 0.5f * v * (1.0f + erff(v * 0.70710678118654752f));
      else if (act == 3) v = 1.0f / (1.0f + expf(-v));
      if (gate) v *= gate[(size_t)r * N + n];
      if (res) v += res[(size_t)r * N + n];
      out[(size_t)r * N + n] = v;
    }
  }
}

// LayerNorm over 512 for row bid. (R5 ln_k body)
__device__ __forceinline__ void ln_stage(int bid, const float* __restrict__ x,
                                         const float* __restrict__ g,
                                         const float* __restrict__ bt,
                                         float* __restrict__ y,
                                         float* __restrict__ rs,
                                         float* __restrict__ rss) {
  if (bid >= 64) return;
  const int b = bid, t = threadIdx.x;
  float2 v = *(const float2*)(x + b * DD + t * 2);
  float s = v.x + v.y;
  float ss = v.x * v.x + v.y * v.y;
#pragma unroll
  for (int o = 32; o; o >>= 1) {
    s += __shfl_down(s, o);
    ss += __shfl_down(ss, o);
  }
  const int w = t >> 6;
  if ((t & 63) == 0) { rs[w] = s; rss[w] = ss; }
  __syncthreads();
  s = rs[0] + rs[1] + rs[2] + rs[3];
  ss = rss[0] + rss[1] + rss[2] + rss[3];
  float m = s * (1.0f / DD);
  float var = ss * (1.0f / DD) - m * m;
  float inv = rsqrtf(var + 1e-5f);
  float2 gg = *(const float2*)(g + t * 2);
  float2 bb = *(const float2*)(bt + t * 2);
  float2 o2;
  o2.x = (v.x - m) * inv * gg.x + bb.x;
  o2.y = (v.y - m) * inv * gg.y + bb.y;
  *(float2*)(y + b * DD + t * 2) = o2;
}

__global__ __launch_bounds__(256) void mlp_coop(MlpParams p) {
  cg::grid_group grid = cg::this_grid();
  __shared__ float As[16 * 34];
  __shared__ float rs[4], rss[4];
  __shared__ float vals[20];
  __shared__ int bestIdx;
  const int bid = blockIdx.x;
  const int tid = threadIdx.x;

  // stage 0: offs[k] = ||c_k||^2 - 2*dot(gram_b, c_k)
  if (bid < 20 && tid < 64) {
    const int k = bid;
    float a = 0.f;
    for (int r = tid; r < GR; r += 64) {
      float c = p.centers[k * GR + r];
      a += c * c - 2.0f * p.gram_b[r] * c;
    }
#pragma unroll
    for (int o = 32; o; o >>= 1) a += __shfl_down(a, o);
    if (tid == 0) p.offs[k] = a;
  }
  // stage 1: h1 = relu(x_embed @ attn_w1 + b1)
  lin_stage(bid, p.x_embed, p.attn_w1, p.attn_b1, nullptr, nullptr, p.h1, 512,
            512, 1, As);
  grid.sync();
  // stage 2: x_attn = sigmoid(h1 @ attn_w2 + b2) * x_embed
  lin_stage(bid, p.h1, p.attn_w2, p.attn_b2, p.x_embed, nullptr, p.x_attn, 512,
            512, 3, As);
  grid.sync();
  // stage 3: xln = LN(x_attn)
  ln_stage(bid, p.x_attn, p.ln_ff_g, p.ln_ff_b, p.xln, rs, rss);
  grid.sync();
  // stage 4: f1 = gelu(xln @ ff_w1 + b1)
  lin_stage(bid, p.xln, p.ff_w1, p.ff_b1, nullptr, nullptr, p.f1, 2048, 512, 2,
            As);
  grid.sync();
  // stage 5: x_main = f1 @ ff_w2 + b2 + x_attn
  lin_stage(bid, p.f1, p.ff_w2, p.ff_b2, nullptr, p.x_attn, p.x_main, 512,
            2048, 0, As);
  grid.sync();
  // stage 6: argmin + concat
  if (bid < 64) {
    const int b = bid;
    if (tid < 20) {
      float s = 0.f;
      for (int sl = 0; sl < 512; ++sl)
        s += p.P[(size_t)sl * 1280 + tid * 64 + b];
      vals[tid] = p.offs[tid] - 2.0f * s;
    }
    __syncthreads();
    if (tid == 0) {
      float best = vals[0];
      int bi = 0;
      for (int k = 1; k < 20; ++k)
        if (vals[k] < best) { best = vals[k]; bi = k; }
      bestIdx = bi;
    }
    __syncthreads();
    const int bi = bestIdx;
#pragma unroll
    for (int q = 0; q < 4; ++q) {
      const int i = q * 256 + tid;
      p.x_fused[(size_t)b * 1024 + i] =
          (i < 512) ? p.x_main[(size_t)b * 512 + i]
                    : p.centers[(size_t)bi * 512 + (i - 512)];
    }
  }
  grid.sync();
  // stage 7: x_h = gelu(x_fused @ gm_w + gm_b)
  lin_stage(bid, p.x_fused, p.gm_w, p.gm_b, nullptr, nullptr, p.x_h, 512, 1024,
            2, As);
  grid.sync();
  // stage 8: xln1 = LN(x_h)
  ln_stage(bid, p.x_h, p.ln1_g, p.ln1_b, p.xln1, rs, rss);
  grid.sync();
  // stage 9: hh = gelu(xln1 @ m1_w + m1_b) + x_h
  lin_stage(bid, p.xln1, p.m1_w, p.m1_b, nullptr, p.x_h, p.hh, 512, 512, 2, As);
  grid.sync();
  // stage 10: h2 = gelu(hh @ m2_w1 + b1)
  lin_stage(bid, p.hh, p.m2_w1, p.m2_b1, nullptr, nullptr, p.h2, 512, 512, 2,
            As);
  grid.sync();
  // stage 11: h3 = gelu(h2 @ m2_w2 + b2)
  lin_stage(bid, p.h2, p.m2_w2, p.m2_b2, nullptr, nullptr, p.h3, 256, 512, 2,
            As);
  grid.sync();
  // stage 12: logits = h3 @ out_w + out_b
  lin_stage(bid, p.h3, p.out_w, p.out_b, nullptr, nullptr, p.out, 10, 256, 0,
            As);
}

// ---------------------------------------------------------------------------
extern "C" void kernel_launch(void* const* d_in, const int* in_sizes, int n_in,
                              void* d_out, int out_size, void* d_ws,
                              size_t ws_size, hipStream_t stream) {
  const float* x_embed = (const float*)d_in[0];
  const float* x_image = (const float*)d_in[1];
  const float* attn_w1 = (const float*)d_in[2];
  const float* attn_b1 = (const float*)d_in[3];
  const float* attn_w2 = (const float*)d_in[4];
  const float* attn_b2 = (const float*)d_in[5];
  const float* ln_ff_g = (const float*)d_in[6];
  const float* ln_ff_b = (const float*)d_in[7];
  const float* ff_w1 = (const float*)d_in[8];
  const float* ff_b1 = (const float*)d_in[9];
  const float* ff_w2 = (const float*)d_in[10];
  const float* ff_b2 = (const float*)d_in[11];
  const float* gram_w = (const float*)d_in[12];
  const float* gram_b = (const float*)d_in[13];
  const float* centers = (const float*)d_in[14];
  const float* gm_w = (const float*)d_in[15];
  const float* gm_b = (const float*)d_in[16];
  const float* ln1_g = (const float*)d_in[17];
  const float* ln1_b = (const float*)d_in[18];
  const float* m1_w = (const float*)d_in[19];
  const float* m1_b = (const float*)d_in[20];
  const float* m2_w1 = (const float*)d_in[21];
  const float* m2_b1 = (const float*)d_in[22];
  const float* m2_w2 = (const float*)d_in[23];
  const float* m2_b2 = (const float*)d_in[24];
  const float* out_w = (const float*)d_in[25];
  const float* out_b = (const float*)d_in[26];

  float* ws = (float*)d_ws;
  size_t off = 0;
  auto alloc = [&](size_t nelem) {
    float* p = ws + off;
    off += (nelem + 63) & ~(size_t)63;
    return p;
  };
  float* G = alloc((size_t)BB * CC * CC);   // 67 MB
  float* U = alloc((size_t)CC * CC * KK);   // 21 MB
  float* P = alloc((size_t)512 * 1280);     // 2.6 MB
  float* offs = alloc(64);
  float* h1 = alloc(BB * DD);
  float* x_attn = alloc(BB * DD);
  float* xln = alloc(BB * DD);
  float* f1 = alloc(BB * 4 * DD);
  float* x_main = alloc(BB * DD);
  float* x_fused = alloc(BB * (DD + GR));
  float* x_h = alloc(BB * DD);
  float* xln1 = alloc(BB * DD);
  float* hh = alloc(BB * DD);
  float* h2 = alloc(BB * DD);
  float* h3 = alloc(BB * (DD / 2));

  // --- Gram branch ---
  hipFuncSetAttribute(reinterpret_cast<const void*>(gram_mfma),
                      hipFuncAttributeMaxDynamicSharedMemorySize, 65536);
  gram_mfma<<<640, 512, 65536, stream>>>(x_image, G);
  u_kernel2<<<1024, 256, 0, stream>>>(gram_w, centers, U);
  scores_k<<<512, 128, 0, stream>>>(G, U, P);

  // --- everything else: one cooperative kernel ---
  MlpParams mp;
  mp.x_embed = x_embed;
  mp.attn_w1 = attn_w1; mp.attn_b1 = attn_b1;
  mp.attn_w2 = attn_w2; mp.attn_b2 = attn_b2;
  mp.ln_ff_g = ln_ff_g; mp.ln_ff_b = ln_ff_b;
  mp.ff_w1 = ff_w1; mp.ff_b1 = ff_b1;
  mp.ff_w2 = ff_w2; mp.ff_b2 = ff_b2;
  mp.gram_b = gram_b; mp.centers = centers;
  mp.gm_w = gm_w; mp.gm_b = gm_b;
  mp.ln1_g = ln1_g; mp.ln1_b = ln1_b;
  mp.m1_w = m1_w; mp.m1_b = m1_b;
  mp.m2_w1 = m2_w1; mp.m2_b1 = m2_b1;
  mp.m2_w2 = m2_w2; mp.m2_b2 = m2_b2;
  mp.out_w = out_w; mp.out_b = out_b;
  mp.P = P;
  mp.offs = offs; mp.h1 = h1; mp.x_attn = x_attn; mp.xln = xln; mp.f1 = f1;
  mp.x_main = x_main; mp.x_fused = x_fused; mp.x_h = x_h; mp.xln1 = xln1;
  mp.hh = hh; mp.h2 = h2; mp.h3 = h3; mp.out = (float*)d_out;

  void* kargs[] = {&mp};
  hipLaunchCooperativeKernel(reinterpret_cast<void*>(mlp_coop), dim3(128),
                             dim3(256), kargs, 0, stream);
}

// Round 7
// 719.531 us; speedup vs baseline: 1.1292x; 1.1292x over previous
//
#include <hip/hip_runtime.h>
#include <math.h>

#define BB 64
#define CC 512
#define HW 784
#define DD 512
#define GR 512
#define KK 20

typedef __bf16 bf16x8 __attribute__((ext_vector_type(8)));
typedef float f32x16 __attribute__((ext_vector_type(16)));

__device__ inline unsigned short bf16rtn(float f) {
  unsigned int u = __builtin_bit_cast(unsigned int, f);
  unsigned int r = (u + 0x7FFFu + ((u >> 16) & 1u)) >> 16;
  return (unsigned short)r;
}

// ---------------------------------------------------------------------------
// fused_A: one dispatch containing three INDEPENDENT works (no cross-block
// deps, no grid sync):
//   - 640 gram blocks: G[b] = xf[b]@xf[b]^T/784  (bf16 MFMA, 128x128 tiles)
//   - 512 u blocks:    U = gram_w @ centers^T    (fp32, BK=32 single-pass)
//   -  20 offs blocks: offs[k] = ||c_k||^2 - 2<gram_b,c_k>
// Interleave 5:4 so both heavy types are co-resident: gram is MFMA/LDS-bound,
// u is HBM-bound -> complementary pipes overlap.
// 512 thr, 76.8 KB dynamic LDS -> 2 blocks/CU; launch_bounds caps VGPR<=128.
// ---------------------------------------------------------------------------
__device__ __forceinline__ void gram_body(int gid, const float* __restrict__ X,
                                          float* __restrict__ G,
                                          unsigned short* __restrict__ Apl,
                                          unsigned short* __restrict__ Bpl) {
  const int b = gid / 10;
  int lin = gid % 10;
  int i = 0;
  while (lin >= 4 - i) { lin -= 4 - i; ++i; }
  const int j = i + lin;  // i <= j
  const bool diag = (i == j);

  const float* __restrict__ xb = X + (size_t)b * (CC * HW);
  const int tid = threadIdx.x;
  const int w = tid >> 6, l = tid & 63;
  const int wr = w >> 1;
  const int wc = w & 1;

  f32x16 acc0 = {};
  f32x16 acc1 = {};

  const int sr = tid >> 2;
  const int lane4 = tid & 3;

  for (int it = 0; it < 7; ++it) {
    const int k0 = it * 112;
    __syncthreads();
#pragma unroll
    for (int q = 0; q < 7; ++q) {
      const int pos = lane4 + q * 4;
      const int chunk = pos >> 1;
      const int soff =
          sr * 128 + (((chunk ^ (sr & 7)) << 3) | ((pos & 1) << 2));
#pragma unroll
      for (int pnl = 0; pnl < 2; ++pnl) {
        if (pnl && diag) break;
        const int rowbase = (pnl ? j : i) * 128;
        float4 v =
            *(const float4*)(xb + (size_t)(rowbase + sr) * HW + k0 + pos * 4);
        unsigned int p0 = bf16rtn(v.x) | ((unsigned int)bf16rtn(v.y) << 16);
        unsigned int p1 = bf16rtn(v.z) | ((unsigned int)bf16rtn(v.w) << 16);
        *(uint2*)((pnl ? Bpl : Apl) + soff) = make_uint2(p0, p1);
      }
    }
    __syncthreads();
    const unsigned short* __restrict__ bP = diag ? Apl : Bpl;
#pragma unroll
    for (int ks = 0; ks < 7; ++ks) {
      const int chunk = ks * 2 + (l >> 5);
      const int ar = wr * 32 + (l & 31);
      bf16x8 a = *(const bf16x8*)(Apl + ar * 128 + ((chunk ^ (ar & 7)) << 3));
      const int br0 = wc * 64 + (l & 31);
      const int br1 = br0 + 32;
      bf16x8 b0 = *(const bf16x8*)(bP + br0 * 128 + ((chunk ^ (br0 & 7)) << 3));
      bf16x8 b1 = *(const bf16x8*)(bP + br1 * 128 + ((chunk ^ (br1 & 7)) << 3));
      acc0 = __builtin_amdgcn_mfma_f32_32x32x16_bf16(a, b0, acc0, 0, 0, 0);
      acc1 = __builtin_amdgcn_mfma_f32_32x32x16_bf16(a, b1, acc1, 0, 0, 0);
    }
  }

  const float sc = 1.0f / (float)HW;
  float* __restrict__ gb = G + (size_t)b * (CC * CC);
  const int rowbase = i * 128 + wr * 32 + 4 * (l >> 5);
  const int colbase = j * 128 + wc * 64 + (l & 31);
#pragma unroll
  for (int n = 0; n < 2; ++n) {
    const f32x16 a = n ? acc1 : acc0;
#pragma unroll
    for (int reg = 0; reg < 16; ++reg) {
      const int row = rowbase + (reg & 3) + 8 * (reg >> 2);
      const int col = colbase + n * 32;
      const float v = a[reg] * sc;
      gb[(size_t)row * CC + col] = v;
      if (!diag) gb[(size_t)col * CC + row] = v;
    }
  }
}

__device__ __forceinline__ void u_body(int uid, const float* __restrict__ W,
                                       const float* __restrict__ C,
                                       float* __restrict__ U,
                                       float* __restrict__ Ws /*[512][36]*/,
                                       float* __restrict__ Ct /*[20][36]*/) {
  const int tid = threadIdx.x;
  const int rt = tid >> 2, kq = tid & 3;  // rt 0..127
  const size_t row0 = (size_t)uid << 9;   // 512 rows per block

  float acc[4][5] = {};

  for (int k0 = 0; k0 < GR; k0 += 32) {
    __syncthreads();
#pragma unroll
    for (int q = 0; q < 8; ++q) {
      const int row = q * 64 + (tid >> 3);
      const int col = (tid & 7) * 4;
      float4 w4 = *(const float4*)(W + (row0 + row) * GR + k0 + col);
      *(float4*)&Ws[row * 36 + col] = w4;
    }
    if (tid < 160) {
      const int k = tid >> 3, pp = tid & 7;
      *(float4*)&Ct[k * 36 + pp * 4] = *(const float4*)(C + k * GR + k0 + pp * 4);
    }
    __syncthreads();
#pragma unroll
    for (int kk4 = 0; kk4 < 8; ++kk4) {
      float4 wv[4];
#pragma unroll
      for (int u = 0; u < 4; ++u)
        wv[u] = *(const float4*)&Ws[(rt + u * 128) * 36 + kk4 * 4];
#pragma unroll
      for (int q = 0; q < 5; ++q) {
        float4 c4 = *(const float4*)&Ct[(kq * 5 + q) * 36 + kk4 * 4];
#pragma unroll
        for (int u = 0; u < 4; ++u) {
          acc[u][q] = fmaf(wv[u].x, c4.x, acc[u][q]);
          acc[u][q] = fmaf(wv[u].y, c4.y, acc[u][q]);
          acc[u][q] = fmaf(wv[u].z, c4.z, acc[u][q]);
          acc[u][q] = fmaf(wv[u].w, c4.w, acc[u][q]);
        }
      }
    }
  }
#pragma unroll
  for (int u = 0; u < 4; ++u)
#pragma unroll
    for (int q = 0; q < 5; ++q)
      U[(row0 + rt + u * 128) * KK + kq * 5 + q] = acc[u][q];
}

__global__ __launch_bounds__(512, 4) void fused_A(
    const float* __restrict__ X, const float* __restrict__ Wg,
    const float* __restrict__ C, const float* __restrict__ gbias,
    float* __restrict__ G, float* __restrict__ U, float* __restrict__ offs) {
  extern __shared__ float ldsf[];  // 76800 B
  const int bid = blockIdx.x;
  if (bid < 1152) {
    const int g = bid / 9, r = bid % 9;
    if (r < 5) {
      gram_body(g * 5 + r, X, G, (unsigned short*)ldsf,
                (unsigned short*)ldsf + 16384);
    } else {
      u_body(g * 4 + (r - 5), Wg, C, U, ldsf, ldsf + 512 * 36);
    }
  } else {
    const int k = bid - 1152, t = threadIdx.x;
    if (t < 64) {
      float a = 0.f;
      for (int r2 = t; r2 < GR; r2 += 64) {
        float c = C[k * GR + r2];
        a += c * c - 2.0f * gbias[r2] * c;
      }
#pragma unroll
      for (int o = 32; o; o >>= 1) a += __shfl_down(a, o);
      if (t == 0) offs[k] = a;
    }
  }
}

// ---------------------------------------------------------------------------
// scores: partial[slice][k][b] = sum_{cd in slice} G[b][cd]*U[cd][k]
// grid 512 (slices of 512 cd), block 128.  (identical to R2/R5)
// ---------------------------------------------------------------------------
__global__ __launch_bounds__(128) void scores_k(const float* __restrict__ G,
                                                const float* __restrict__ U,
                                                float* __restrict__ P) {
  __shared__ float Gs[64][68];
  __shared__ float Ut[20][68];

  const int tid = threadIdx.x;
  const int bsub = tid & 31, kg = tid >> 5;
  const size_t s0 = (size_t)blockIdx.x << 9;

  float acc[2][5] = {};

  for (int c0 = 0; c0 < 512; c0 += 64) {
    __syncthreads();
#pragma unroll
    for (int q = 0; q < 8; ++q) {
      int bb = q * 8 + (tid >> 4);
      float4 g4 = *(const float4*)(G + (size_t)bb * (CC * CC) + s0 + c0 +
                                   (tid & 15) * 4);
      *(float4*)&Gs[bb][(tid & 15) * 4] = g4;
    }
#pragma unroll
    for (int e = 0; e < 10; ++e) {
      int f = e * 128 + tid;
      float val = U[(s0 + c0) * KK + f];
      Ut[f % 20][f / 20] = val;
    }
    __syncthreads();
#pragma unroll
    for (int kk4 = 0; kk4 < 16; ++kk4) {
      float4 ga = *(const float4*)&Gs[bsub][kk4 * 4];
      float4 gb2 = *(const float4*)&Gs[bsub + 32][kk4 * 4];
#pragma unroll
      for (int q = 0; q < 5; ++q) {
        float4 c4 = *(const float4*)&Ut[kg * 5 + q][kk4 * 4];
        acc[0][q] = fmaf(ga.x, c4.x, acc[0][q]);
        acc[0][q] = fmaf(ga.y, c4.y, acc[0][q]);
        acc[0][q] = fmaf(ga.z, c4.z, acc[0][q]);
        acc[0][q] = fmaf(ga.w, c4.w, acc[0][q]);
        acc[1][q] = fmaf(gb2.x, c4.x, acc[1][q]);
        acc[1][q] = fmaf(gb2.y, c4.y, acc[1][q]);
        acc[1][q] = fmaf(gb2.z, c4.z, acc[1][q]);
        acc[1][q] = fmaf(gb2.w, c4.w, acc[1][q]);
      }
    }
  }
#pragma unroll
  for (int q = 0; q < 5; ++q) {
    P[(size_t)blockIdx.x * 1280 + (kg * 5 + q) * 64 + bsub] = acc[0][q];
    P[(size_t)blockIdx.x * 1280 + (kg * 5 + q) * 64 + bsub + 32] = acc[1][q];
  }
}

// argmin over k, then concat(x_main, centers[idx]) -> x_fused. grid 64, blk 256.
// (R4-validated body, R2/R5 P layout)
__global__ __launch_bounds__(256) void argmin_concat_k(
    const float* __restrict__ P, const float* __restrict__ offs,
    const float* __restrict__ xm, const float* __restrict__ C,
    float* __restrict__ xf) {
  const int b = blockIdx.x, t = threadIdx.x;
  __shared__ float vals[20];
  __shared__ int bestIdx;
  if (t < 20) {
    float s = 0.f;
    for (int sl = 0; sl < 512; ++sl) s += P[(size_t)sl * 1280 + t * 64 + b];
    vals[t] = offs[t] - 2.0f * s;
  }
  __syncthreads();
  if (t == 0) {
    float best = vals[0];
    int bi = 0;
    for (int k = 1; k < 20; ++k)
      if (vals[k] < best) { best = vals[k]; bi = k; }
    bestIdx = bi;
  }
  __syncthreads();
  const int bi = bestIdx;
#pragma unroll
  for (int q = 0; q < 4; ++q) {
    const int i = q * 256 + t;
    xf[(size_t)b * 1024 + i] =
        (i < 512) ? xm[(size_t)b * 512 + i] : C[(size_t)bi * 512 + (i - 512)];
  }
}

// Row LayerNorm over 512.  grid 64, block 256. (R5)
__global__ void ln_k(const float* __restrict__ x, const float* __restrict__ g,
                     const float* __restrict__ bt, float* __restrict__ y) {
  int b = blockIdx.x, t = threadIdx.x;
  float2 v = *(const float2*)(x + b * DD + t * 2);
  float s = v.x + v.y;
  float ss = v.x * v.x + v.y * v.y;
#pragma unroll
  for (int o = 32; o; o >>= 1) {
    s += __shfl_down(s, o);
    ss += __shfl_down(ss, o);
  }
  __shared__ float rs[4], rss[4];
  int w = t >> 6;
  if ((t & 63) == 0) { rs[w] = s; rss[w] = ss; }
  __syncthreads();
  s = rs[0] + rs[1] + rs[2] + rs[3];
  ss = rss[0] + rss[1] + rss[2] + rss[3];
  float m = s * (1.0f / DD);
  float var = ss * (1.0f / DD) - m * m;
  float inv = rsqrtf(var + 1e-5f);
  float2 gg = *(const float2*)(g + t * 2);
  float2 bb = *(const float2*)(bt + t * 2);
  float2 o2;
  o2.x = (v.x - m) * inv * gg.x + bb.x;
  o2.y = (v.y - m) * inv * gg.y + bb.y;
  *(float2*)(y + b * DD + t * 2) = o2;
}

// ---------------------------------------------------------------------------
// Generic small GEMM: out = post(act(A@W + bias)).  M=64 rows. (R2/R5)
// grid ((N+63)/64, 4), block (64,4). ACT: 0 none, 1 relu, 2 gelu, 3 sigmoid.
// ---------------------------------------------------------------------------
template <int ACT, bool GATE, bool RES>
__global__ __launch_bounds__(256) void linear_k(
    const float* __restrict__ A, const float* __restrict__ W,
    const float* __restrict__ bias, const float* __restrict__ gate,
    const float* __restrict__ res, float* __restrict__ out, int N, int K) {
  __shared__ float As[16][34];
  const int tx = threadIdx.x, ty = threadIdx.y;
  const int n = blockIdx.x * 64 + tx;
  const int r0 = blockIdx.y * 16;
  float acc[4] = {0.f, 0.f, 0.f, 0.f};
  const int t2 = (ty * 64 + tx) * 2;
  const int srr = t2 >> 5, skk = t2 & 31;

  for (int k0 = 0; k0 < K; k0 += 32) {
    __syncthreads();
    float2 a2 = *(const float2*)(A + (size_t)(r0 + srr) * K + k0 + skk);
    As[srr][skk] = a2.x;
    As[srr][skk + 1] = a2.y;
    __syncthreads();
    if (n < N) {
#pragma unroll
      for (int kk = 0; kk < 32; ++kk) {
        float w = W[(size_t)(k0 + kk) * N + n];
#pragma unroll
        for (int u = 0; u < 4; ++u)
          acc[u] = fmaf(As[ty * 4 + u][kk], w, acc[u]);
      }
    }
  }
  if (n < N) {
    float bv = bias[n];
#pragma unroll
    for (int u = 0; u < 4; ++u) {
      int r = r0 + ty * 4 + u;
      float v = acc[u] + bv;
      if (ACT == 1) v = v > 0.f ? v : 0.f;
      else if (ACT == 2) v = 0.5f * v * (1.0f + erff(v * 0.70710678118654752f));
      else if (ACT == 3) v = 1.0f / (1.0f + expf(-v));
      if (GATE) v *= gate[(size_t)r * N + n];
      if (RES) v += res[(size_t)r * N + n];
      out[(size_t)r * N + n] = v;
    }
  }
}

// ---------------------------------------------------------------------------
extern "C" void kernel_launch(void* const* d_in, const int* in_sizes, int n_in,
                              void* d_out, int out_size, void* d_ws,
                              size_t ws_size, hipStream_t stream) {
  const float* x_embed = (const float*)d_in[0];
  const float* x_image = (const float*)d_in[1];
  const float* attn_w1 = (const float*)d_in[2];
  const float* attn_b1 = (const float*)d_in[3];
  const float* attn_w2 = (const float*)d_in[4];
  const float* attn_b2 = (const float*)d_in[5];
  const float* ln_ff_g = (const float*)d_in[6];
  const float* ln_ff_b = (const float*)d_in[7];
  const float* ff_w1 = (const float*)d_in[8];
  const float* ff_b1 = (const float*)d_in[9];
  const float* ff_w2 = (const float*)d_in[10];
  const float* ff_b2 = (const float*)d_in[11];
  const float* gram_w = (const float*)d_in[12];
  const float* gram_b = (const float*)d_in[13];
  const float* centers = (const float*)d_in[14];
  const float* gm_w = (const float*)d_in[15];
  const float* gm_b = (const float*)d_in[16];
  const float* ln1_g = (const float*)d_in[17];
  const float* ln1_b = (const float*)d_in[18];
  const float* m1_w = (const float*)d_in[19];
  const float* m1_b = (const float*)d_in[20];
  const float* m2_w1 = (const float*)d_in[21];
  const float* m2_b1 = (const float*)d_in[22];
  const float* m2_w2 = (const float*)d_in[23];
  const float* m2_b2 = (const float*)d_in[24];
  const float* out_w = (const float*)d_in[25];
  const float* out_b = (const float*)d_in[26];

  float* ws = (float*)d_ws;
  size_t off = 0;
  auto alloc = [&](size_t nelem) {
    float* p = ws + off;
    off += (nelem + 63) & ~(size_t)63;
    return p;
  };
  float* G = alloc((size_t)BB * CC * CC);   // 67 MB
  float* U = alloc((size_t)CC * CC * KK);   // 21 MB
  float* P = alloc((size_t)512 * 1280);     // 2.6 MB
  float* offs = alloc(64);
  float* h1 = alloc(BB * DD);
  float* x_attn = alloc(BB * DD);
  float* xln = alloc(BB * DD);
  float* f1 = alloc(BB * 4 * DD);
  float* x_main = alloc(BB * DD);
  float* x_fused = alloc(BB * (DD + GR));
  float* x_h = alloc(BB * DD);
  float* xln1 = alloc(BB * DD);
  float* hh = alloc(BB * DD);
  float* h2 = alloc(BB * DD);
  float* h3 = alloc(BB * (DD / 2));

  // --- fused front-end: gram + U + offs in one dispatch ---
  hipFuncSetAttribute(reinterpret_cast<const void*>(fused_A),
                      hipFuncAttributeMaxDynamicSharedMemorySize, 76800);
  fused_A<<<1172, 512, 76800, stream>>>(x_image, gram_w, centers, gram_b, G, U,
                                        offs);
  scores_k<<<512, 128, 0, stream>>>(G, U, P);

  // --- MLP branch ---
  dim3 blk(64, 4);
  linear_k<1, false, false><<<dim3(8, 4), blk, 0, stream>>>(
      x_embed, attn_w1, attn_b1, nullptr, nullptr, h1, 512, 512);
  linear_k<3, true, false><<<dim3(8, 4), blk, 0, stream>>>(
      h1, attn_w2, attn_b2, x_embed, nullptr, x_attn, 512, 512);
  ln_k<<<64, 256, 0, stream>>>(x_attn, ln_ff_g, ln_ff_b, xln);
  linear_k<2, false, false><<<dim3(32, 4), blk, 0, stream>>>(
      xln, ff_w1, ff_b1, nullptr, nullptr, f1, 2048, 512);
  linear_k<0, false, true><<<dim3(8, 4), blk, 0, stream>>>(
      f1, ff_w2, ff_b2, nullptr, x_attn, x_main, 512, 2048);

  // --- fuse ---
  argmin_concat_k<<<64, 256, 0, stream>>>(P, offs, x_main, centers, x_fused);
  linear_k<2, false, false><<<dim3(8, 4), blk, 0, stream>>>(
      x_fused, gm_w, gm_b, nullptr, nullptr, x_h, 512, 1024);
  ln_k<<<64, 256, 0, stream>>>(x_h, ln1_g, ln1_b, xln1);
  linear_k<2, false, true><<<dim3(8, 4), blk, 0, stream>>>(
      xln1, m1_w, m1_b, nullptr, x_h, hh, 512, 512);
  linear_k<2, false, false><<<dim3(8, 4), blk, 0, stream>>>(
      hh, m2_w1, m2_b1, nullptr, nullptr, h2, 512, 512);
  linear_k<2, false, false><<<dim3(4, 4), blk, 0, stream>>>(
      h2, m2_w2, m2_b2, nullptr, nullptr, h3, 256, 512);
  linear_k<0, false, false><<<dim3(1, 4), blk, 0, stream>>>(
      h3, out_w, out_b, nullptr, nullptr, (float*)d_out, 10, 256);
}

// Round 8
// 598.995 us; speedup vs baseline: 1.3565x; 1.2012x over previous
//
#include <hip/hip_runtime.h>
#include <math.h>

#define BB 64
#define CC 512
#define HW 784
#define DD 512
#define GR 512
#define KK 20

typedef __bf16 bf16x8 __attribute__((ext_vector_type(8)));
typedef float f32x16 __attribute__((ext_vector_type(16)));

__device__ inline unsigned short bf16rtn(float f) {
  unsigned int u = __builtin_bit_cast(unsigned int, f);
  unsigned int r = (u + 0x7FFFu + ((u >> 16) & 1u)) >> 16;
  return (unsigned short)r;
}

// ---------------------------------------------------------------------------
// fused_A: gram (640 blocks) + U (512 blocks) + offs (20 blocks), independent.
// (identical to R7)
// ---------------------------------------------------------------------------
__device__ __forceinline__ void gram_body(int gid, const float* __restrict__ X,
                                          float* __restrict__ G,
                                          unsigned short* __restrict__ Apl,
                                          unsigned short* __restrict__ Bpl) {
  const int b = gid / 10;
  int lin = gid % 10;
  int i = 0;
  while (lin >= 4 - i) { lin -= 4 - i; ++i; }
  const int j = i + lin;  // i <= j
  const bool diag = (i == j);

  const float* __restrict__ xb = X + (size_t)b * (CC * HW);
  const int tid = threadIdx.x;
  const int w = tid >> 6, l = tid & 63;
  const int wr = w >> 1;
  const int wc = w & 1;

  f32x16 acc0 = {};
  f32x16 acc1 = {};

  const int sr = tid >> 2;
  const int lane4 = tid & 3;

  for (int it = 0; it < 7; ++it) {
    const int k0 = it * 112;
    __syncthreads();
#pragma unroll
    for (int q = 0; q < 7; ++q) {
      const int pos = lane4 + q * 4;
      const int chunk = pos >> 1;
      const int soff =
          sr * 128 + (((chunk ^ (sr & 7)) << 3) | ((pos & 1) << 2));
#pragma unroll
      for (int pnl = 0; pnl < 2; ++pnl) {
        if (pnl && diag) break;
        const int rowbase = (pnl ? j : i) * 128;
        float4 v =
            *(const float4*)(xb + (size_t)(rowbase + sr) * HW + k0 + pos * 4);
        unsigned int p0 = bf16rtn(v.x) | ((unsigned int)bf16rtn(v.y) << 16);
        unsigned int p1 = bf16rtn(v.z) | ((unsigned int)bf16rtn(v.w) << 16);
        *(uint2*)((pnl ? Bpl : Apl) + soff) = make_uint2(p0, p1);
      }
    }
    __syncthreads();
    const unsigned short* __restrict__ bP = diag ? Apl : Bpl;
#pragma unroll
    for (int ks = 0; ks < 7; ++ks) {
      const int chunk = ks * 2 + (l >> 5);
      const int ar = wr * 32 + (l & 31);
      bf16x8 a = *(const bf16x8*)(Apl + ar * 128 + ((chunk ^ (ar & 7)) << 3));
      const int br0 = wc * 64 + (l & 31);
      const int br1 = br0 + 32;
      bf16x8 b0 = *(const bf16x8*)(bP + br0 * 128 + ((chunk ^ (br0 & 7)) << 3));
      bf16x8 b1 = *(const bf16x8*)(bP + br1 * 128 + ((chunk ^ (br1 & 7)) << 3));
      acc0 = __builtin_amdgcn_mfma_f32_32x32x16_bf16(a, b0, acc0, 0, 0, 0);
      acc1 = __builtin_amdgcn_mfma_f32_32x32x16_bf16(a, b1, acc1, 0, 0, 0);
    }
  }

  const float sc = 1.0f / (float)HW;
  float* __restrict__ gb = G + (size_t)b * (CC * CC);
  const int rowbase = i * 128 + wr * 32 + 4 * (l >> 5);
  const int colbase = j * 128 + wc * 64 + (l & 31);
#pragma unroll
  for (int n = 0; n < 2; ++n) {
    const f32x16 a = n ? acc1 : acc0;
#pragma unroll
    for (int reg = 0; reg < 16; ++reg) {
      const int row = rowbase + (reg & 3) + 8 * (reg >> 2);
      const int col = colbase + n * 32;
      const float v = a[reg] * sc;
      gb[(size_t)row * CC + col] = v;
      if (!diag) gb[(size_t)col * CC + row] = v;
    }
  }
}

__device__ __forceinline__ void u_body(int uid, const float* __restrict__ W,
                                       const float* __restrict__ C,
                                       float* __restrict__ U,
                                       float* __restrict__ Ws /*[512][36]*/,
                                       float* __restrict__ Ct /*[20][36]*/) {
  const int tid = threadIdx.x;
  const int rt = tid >> 2, kq = tid & 3;
  const size_t row0 = (size_t)uid << 9;

  float acc[4][5] = {};

  for (int k0 = 0; k0 < GR; k0 += 32) {
    __syncthreads();
#pragma unroll
    for (int q = 0; q < 8; ++q) {
      const int row = q * 64 + (tid >> 3);
      const int col = (tid & 7) * 4;
      float4 w4 = *(const float4*)(W + (row0 + row) * GR + k0 + col);
      *(float4*)&Ws[row * 36 + col] = w4;
    }
    if (tid < 160) {
      const int k = tid >> 3, pp = tid & 7;
      *(float4*)&Ct[k * 36 + pp * 4] = *(const float4*)(C + k * GR + k0 + pp * 4);
    }
    __syncthreads();
#pragma unroll
    for (int kk4 = 0; kk4 < 8; ++kk4) {
      float4 wv[4];
#pragma unroll
      for (int u = 0; u < 4; ++u)
        wv[u] = *(const float4*)&Ws[(rt + u * 128) * 36 + kk4 * 4];
#pragma unroll
      for (int q = 0; q < 5; ++q) {
        float4 c4 = *(const float4*)&Ct[(kq * 5 + q) * 36 + kk4 * 4];
#pragma unroll
        for (int u = 0; u < 4; ++u) {
          acc[u][q] = fmaf(wv[u].x, c4.x, acc[u][q]);
          acc[u][q] = fmaf(wv[u].y, c4.y, acc[u][q]);
          acc[u][q] = fmaf(wv[u].z, c4.z, acc[u][q]);
          acc[u][q] = fmaf(wv[u].w, c4.w, acc[u][q]);
        }
      }
    }
  }
#pragma unroll
  for (int u = 0; u < 4; ++u)
#pragma unroll
    for (int q = 0; q < 5; ++q)
      U[(row0 + rt + u * 128) * KK + kq * 5 + q] = acc[u][q];
}

__global__ __launch_bounds__(512, 4) void fused_A(
    const float* __restrict__ X, const float* __restrict__ Wg,
    const float* __restrict__ C, const float* __restrict__ gbias,
    float* __restrict__ G, float* __restrict__ U, float* __restrict__ offs) {
  extern __shared__ float ldsf[];
  const int bid = blockIdx.x;
  if (bid < 1152) {
    const int g = bid / 9, r = bid % 9;
    if (r < 5) {
      gram_body(g * 5 + r, X, G, (unsigned short*)ldsf,
                (unsigned short*)ldsf + 16384);
    } else {
      u_body(g * 4 + (r - 5), Wg, C, U, ldsf, ldsf + 512 * 36);
    }
  } else {
    const int k = bid - 1152, t = threadIdx.x;
    if (t < 64) {
      float a = 0.f;
      for (int r2 = t; r2 < GR; r2 += 64) {
        float c = C[k * GR + r2];
        a += c * c - 2.0f * gbias[r2] * c;
      }
#pragma unroll
      for (int o = 32; o; o >>= 1) a += __shfl_down(a, o);
      if (t == 0) offs[k] = a;
    }
  }
}

// ---------------------------------------------------------------------------
// scores: partial[slice][k][b] = sum_{cd in slice} G[b][cd]*U[cd][k]
// grid 512, block 128. (identical to R2/R5/R7)
// ---------------------------------------------------------------------------
__global__ __launch_bounds__(128) void scores_k(const float* __restrict__ G,
                                                const float* __restrict__ U,
                                                float* __restrict__ P) {
  __shared__ float Gs[64][68];
  __shared__ float Ut[20][68];

  const int tid = threadIdx.x;
  const int bsub = tid & 31, kg = tid >> 5;
  const size_t s0 = (size_t)blockIdx.x << 9;

  float acc[2][5] = {};

  for (int c0 = 0; c0 < 512; c0 += 64) {
    __syncthreads();
#pragma unroll
    for (int q = 0; q < 8; ++q) {
      int bb = q * 8 + (tid >> 4);
      float4 g4 = *(const float4*)(G + (size_t)bb * (CC * CC) + s0 + c0 +
                                   (tid & 15) * 4);
      *(float4*)&Gs[bb][(tid & 15) * 4] = g4;
    }
#pragma unroll
    for (int e = 0; e < 10; ++e) {
      int f = e * 128 + tid;
      float val = U[(s0 + c0) * KK + f];
      Ut[f % 20][f / 20] = val;
    }
    __syncthreads();
#pragma unroll
    for (int kk4 = 0; kk4 < 16; ++kk4) {
      float4 ga = *(const float4*)&Gs[bsub][kk4 * 4];
      float4 gb2 = *(const float4*)&Gs[bsub + 32][kk4 * 4];
#pragma unroll
      for (int q = 0; q < 5; ++q) {
        float4 c4 = *(const float4*)&Ut[kg * 5 + q][kk4 * 4];
        acc[0][q] = fmaf(ga.x, c4.x, acc[0][q]);
        acc[0][q] = fmaf(ga.y, c4.y, acc[0][q]);
        acc[0][q] = fmaf(ga.z, c4.z, acc[0][q]);
        acc[0][q] = fmaf(ga.w, c4.w, acc[0][q]);
        acc[1][q] = fmaf(gb2.x, c4.x, acc[1][q]);
        acc[1][q] = fmaf(gb2.y, c4.y, acc[1][q]);
        acc[1][q] = fmaf(gb2.z, c4.z, acc[1][q]);
        acc[1][q] = fmaf(gb2.w, c4.w, acc[1][q]);
      }
    }
  }
#pragma unroll
  for (int q = 0; q < 5; ++q) {
    P[(size_t)blockIdx.x * 1280 + (kg * 5 + q) * 64 + bsub] = acc[0][q];
    P[(size_t)blockIdx.x * 1280 + (kg * 5 + q) * 64 + bsub + 32] = acc[1][q];
  }
}

// ---------------------------------------------------------------------------
// mlp_row: the ENTIRE post-scores chain, one block per batch row, no grid
// syncs. GEMV per layer: x in LDS; thread (kg,cq) = 4-way k-split x 128 col
// quads; float4 W reads coalesced; LDS reduce over kg. Weights shared by 8
// blocks/XCD -> L2-hit dominated. 64 blocks x 512 thr.
// ---------------------------------------------------------------------------
struct MlpRowParams {
  const float* x_embed;
  const float* attn_w1; const float* attn_b1;
  const float* attn_w2; const float* attn_b2;
  const float* ln_ff_g; const float* ln_ff_b;
  const float* ff_w1; const float* ff_b1;
  const float* ff_w2; const float* ff_b2;
  const float* centers;
  const float* gm_w; const float* gm_b;
  const float* ln1_g; const float* ln1_b;
  const float* m1_w; const float* m1_b;
  const float* m2_w1; const float* m2_b1;
  const float* m2_w2; const float* m2_b2;
  const float* out_w; const float* out_b;
  const float* P; const float* offs;
  float* out;
};

// ACT: 0 none, 1 relu, 2 gelu, 3 sigmoid
template <int ACT, bool GATE, bool RES>
__device__ __forceinline__ void gemv512(const float* __restrict__ x,
                                        const float* __restrict__ W,
                                        const float* __restrict__ bias,
                                        const float* __restrict__ gate,
                                        const float* __restrict__ res,
                                        float* __restrict__ y, int N, int K,
                                        float* __restrict__ part) {
  const int tid = threadIdx.x;
  const int kg = tid >> 7, cq = tid & 127;
  const int kper = K >> 2;
  const int k0 = kg * kper;
  const int nq = N >> 2;
  for (int nq0 = 0; nq0 < nq; nq0 += 128) {
    const int quad = nq0 + cq;
    float4 acc = make_float4(0.f, 0.f, 0.f, 0.f);
    if (quad < nq) {
      const float* Wp = W + (size_t)k0 * N + quad * 4;
#pragma unroll 4
      for (int k = 0; k < kper; ++k) {
        const float xv = x[k0 + k];
        const float4 w = *(const float4*)(Wp + (size_t)k * N);
        acc.x = fmaf(xv, w.x, acc.x);
        acc.y = fmaf(xv, w.y, acc.y);
        acc.z = fmaf(xv, w.z, acc.z);
        acc.w = fmaf(xv, w.w, acc.w);
      }
    }
    __syncthreads();  // part free (prev pass finalize done)
    *(float4*)(part + tid * 4) = acc;
    __syncthreads();
    if (kg == 0 && quad < nq) {
      float4 a0 = *(float4*)(part + (0 * 128 + cq) * 4);
      float4 a1 = *(float4*)(part + (1 * 128 + cq) * 4);
      float4 a2 = *(float4*)(part + (2 * 128 + cq) * 4);
      float4 a3 = *(float4*)(part + (3 * 128 + cq) * 4);
      float4 b4 = *(const float4*)(bias + quad * 4);
      float o[4] = {a0.x + a1.x + a2.x + a3.x + b4.x,
                    a0.y + a1.y + a2.y + a3.y + b4.y,
                    a0.z + a1.z + a2.z + a3.z + b4.z,
                    a0.w + a1.w + a2.w + a3.w + b4.w};
#pragma unroll
      for (int u = 0; u < 4; ++u) {
        float v = o[u];
        if (ACT == 1) v = v > 0.f ? v : 0.f;
        else if (ACT == 2)
          v = 0.5f * v * (1.0f + erff(v * 0.70710678118654752f));
        else if (ACT == 3) v = 1.0f / (1.0f + expf(-v));
        const int n = quad * 4 + u;
        if (GATE) v *= gate[n];
        if (RES) v += res[n];
        y[n] = v;
      }
    }
  }
  __syncthreads();  // y visible to all
}

// LayerNorm over y[512] -> o[512] (block-wide).
__device__ __forceinline__ void ln512(const float* __restrict__ y,
                                      const float* __restrict__ g,
                                      const float* __restrict__ bt,
                                      float* __restrict__ o,
                                      float* __restrict__ red) {
  const int tid = threadIdx.x;
  const float v = y[tid];
  float s = v, ss = v * v;
#pragma unroll
  for (int of = 32; of; of >>= 1) {
    s += __shfl_xor(s, of);
    ss += __shfl_xor(ss, of);
  }
  const int w = tid >> 6;
  if ((tid & 63) == 0) { red[w * 2] = s; red[w * 2 + 1] = ss; }
  __syncthreads();
  s = 0.f; ss = 0.f;
#pragma unroll
  for (int q = 0; q < 8; ++q) { s += red[q * 2]; ss += red[q * 2 + 1]; }
  const float m = s * (1.0f / 512.0f);
  const float inv = rsqrtf(ss * (1.0f / 512.0f) - m * m + 1e-5f);
  o[tid] = (v - m) * inv * g[tid] + bt[tid];
  __syncthreads();
}

__global__ __launch_bounds__(512) void mlp_row(MlpRowParams p) {
  __shared__ float xe[512], h1[512], xa[512], xt[512], f1[2048], xm[512];
  __shared__ float xf[1024], xh[512], hh[512], h2[512], h3[256];
  __shared__ float part[512 * 4];
  __shared__ float red[16];
  __shared__ float ps[16][20];
  __shared__ float vals[20];
  __shared__ int bestIdx;

  const int b = blockIdx.x;
  const int tid = threadIdx.x;

  xe[tid] = p.x_embed[(size_t)b * 512 + tid];
  __syncthreads();

  // 1: h1 = relu(xe@attn_w1 + b1)
  gemv512<1, false, false>(xe, p.attn_w1, p.attn_b1, nullptr, nullptr, h1, 512,
                           512, part);
  // 2: xa = sigmoid(h1@attn_w2 + b2) * xe
  gemv512<3, true, false>(h1, p.attn_w2, p.attn_b2, xe, nullptr, xa, 512, 512,
                          part);
  // 3: xt = LN(xa)
  ln512(xa, p.ln_ff_g, p.ln_ff_b, xt, red);
  // 4: f1 = gelu(xt@ff_w1 + b1)
  gemv512<2, false, false>(xt, p.ff_w1, p.ff_b1, nullptr, nullptr, f1, 2048,
                           512, part);
  // 5: xm = f1@ff_w2 + b2 + xa
  gemv512<0, false, true>(f1, p.ff_w2, p.ff_b2, nullptr, xa, xm, 512, 2048,
                          part);

  // 6: argmin over centers + concat
  {
    const int g = tid >> 5, k = tid & 31;
    if (k < 20) {
      float s = 0.f;
#pragma unroll 4
      for (int m2 = 0; m2 < 32; ++m2)
        s += p.P[(size_t)(g + 16 * m2) * 1280 + k * 64 + b];
      ps[g][k] = s;
    }
    __syncthreads();
    if (tid < 20) {
      float s = 0.f;
#pragma unroll
      for (int q = 0; q < 16; ++q) s += ps[q][tid];
      vals[tid] = p.offs[tid] - 2.0f * s;
    }
    __syncthreads();
    if (tid == 0) {
      float best = vals[0];
      int bi = 0;
      for (int k2 = 1; k2 < 20; ++k2)
        if (vals[k2] < best) { best = vals[k2]; bi = k2; }
      bestIdx = bi;
    }
    __syncthreads();
    xf[tid] = xm[tid];
    xf[512 + tid] = p.centers[(size_t)bestIdx * 512 + tid];
    __syncthreads();
  }

  // 7: xh = gelu(xf@gm_w + gm_b)   (K=1024)
  gemv512<2, false, false>(xf, p.gm_w, p.gm_b, nullptr, nullptr, xh, 512, 1024,
                           part);
  // 8: xt = LN(xh)
  ln512(xh, p.ln1_g, p.ln1_b, xt, red);
  // 9: hh = gelu(xt@m1_w + m1_b) + xh
  gemv512<2, false, true>(xt, p.m1_w, p.m1_b, nullptr, xh, hh, 512, 512, part);
  // 10: h2 = gelu(hh@m2_w1 + b1)
  gemv512<2, false, false>(hh, p.m2_w1, p.m2_b1, nullptr, nullptr, h2, 512,
                           512, part);
  // 11: h3 = gelu(h2@m2_w2 + b2)   (N=256)
  gemv512<2, false, false>(h2, p.m2_w2, p.m2_b2, nullptr, nullptr, h3, 256,
                           512, part);
  // 12: logits = h3@out_w + out_b  (K=256, N=10)
  if (tid < 10) {
    float s = p.out_b[tid];
#pragma unroll 4
    for (int k = 0; k < 256; ++k) s = fmaf(h3[k], p.out_w[k * 10 + tid], s);
    p.out[(size_t)b * 10 + tid] = s;
  }
}

// ---------------------------------------------------------------------------
extern "C" void kernel_launch(void* const* d_in, const int* in_sizes, int n_in,
                              void* d_out, int out_size, void* d_ws,
                              size_t ws_size, hipStream_t stream) {
  const float* x_embed = (const float*)d_in[0];
  const float* x_image = (const float*)d_in[1];
  const float* attn_w1 = (const float*)d_in[2];
  const float* attn_b1 = (const float*)d_in[3];
  const float* attn_w2 = (const float*)d_in[4];
  const float* attn_b2 = (const float*)d_in[5];
  const float* ln_ff_g = (const float*)d_in[6];
  const float* ln_ff_b = (const float*)d_in[7];
  const float* ff_w1 = (const float*)d_in[8];
  const float* ff_b1 = (const float*)d_in[9];
  const float* ff_w2 = (const float*)d_in[10];
  const float* ff_b2 = (const float*)d_in[11];
  const float* gram_w = (const float*)d_in[12];
  const float* gram_b = (const float*)d_in[13];
  const float* centers = (const float*)d_in[14];
  const float* gm_w = (const float*)d_in[15];
  const float* gm_b = (const float*)d_in[16];
  const float* ln1_g = (const float*)d_in[17];
  const float* ln1_b = (const float*)d_in[18];
  const float* m1_w = (const float*)d_in[19];
  const float* m1_b = (const float*)d_in[20];
  const float* m2_w1 = (const float*)d_in[21];
  const float* m2_b1 = (const float*)d_in[22];
  const float* m2_w2 = (const float*)d_in[23];
  const float* m2_b2 = (const float*)d_in[24];
  const float* out_w = (const float*)d_in[25];
  const float* out_b = (const float*)d_in[26];

  float* ws = (float*)d_ws;
  size_t off = 0;
  auto alloc = [&](size_t nelem) {
    float* p = ws + off;
    off += (nelem + 63) & ~(size_t)63;
    return p;
  };
  float* G = alloc((size_t)BB * CC * CC);   // 67 MB
  float* U = alloc((size_t)CC * CC * KK);   // 21 MB
  float* P = alloc((size_t)512 * 1280);     // 2.6 MB
  float* offs = alloc(64);

  // --- fused front-end: gram + U + offs in one dispatch ---
  hipFuncSetAttribute(reinterpret_cast<const void*>(fused_A),
                      hipFuncAttributeMaxDynamicSharedMemorySize, 76800);
  fused_A<<<1172, 512, 76800, stream>>>(x_image, gram_w, centers, gram_b, G, U,
                                        offs);
  scores_k<<<512, 128, 0, stream>>>(G, U, P);

  // --- entire MLP chain: one dispatch, row-parallel ---
  MlpRowParams mp;
  mp.x_embed = x_embed;
  mp.attn_w1 = attn_w1; mp.attn_b1 = attn_b1;
  mp.attn_w2 = attn_w2; mp.attn_b2 = attn_b2;
  mp.ln_ff_g = ln_ff_g; mp.ln_ff_b = ln_ff_b;
  mp.ff_w1 = ff_w1; mp.ff_b1 = ff_b1;
  mp.ff_w2 = ff_w2; mp.ff_b2 = ff_b2;
  mp.centers = centers;
  mp.gm_w = gm_w; mp.gm_b = gm_b;
  mp.ln1_g = ln1_g; mp.ln1_b = ln1_b;
  mp.m1_w = m1_w; mp.m1_b = m1_b;
  mp.m2_w1 = m2_w1; mp.m2_b1 = m2_b1;
  mp.m2_w2 = m2_w2; mp.m2_b2 = m2_b2;
  mp.out_w = out_w; mp.out_b = out_b;
  mp.P = P; mp.offs = offs;
  mp.out = (float*)d_out;
  mlp_row<<<64, 512, 0, stream>>>(mp);
}